// Round 1
// 863.273 us; speedup vs baseline: 1.3020x; 1.3020x over previous
//
#include <hip/hip_runtime.h>
#include <hip/hip_bf16.h>

typedef __bf16 bf16x8 __attribute__((ext_vector_type(8)));
typedef __bf16 bf16x4 __attribute__((ext_vector_type(4)));
typedef float  f32x4  __attribute__((ext_vector_type(4)));
typedef int    i32x4  __attribute__((ext_vector_type(4)));

#define NHEAD 16
#define DKV   64
#define SLEN  2048
#define BATCH 2
#define DMODEL 1024
#define NROWS (BATCH*SLEN) /* 4096 */

static constexpr float INV_TEMP = 0.35355339059327373f; // 1 / 64^0.25

// ---------------------------------------------------------------- LayerNorm
__global__ __launch_bounds__(256) void ln_kernel(const float* __restrict__ q,
    const float* __restrict__ gamma, const float* __restrict__ beta,
    __bf16* __restrict__ qn)
{
  int row = blockIdx.x;
  int t = threadIdx.x;
  const float* x = q + (size_t)row * DMODEL;
  float4 v = *reinterpret_cast<const float4*>(x + t * 4);
  float s  = v.x + v.y + v.z + v.w;
  float ss = v.x * v.x + v.y * v.y + v.z * v.z + v.w * v.w;
#pragma unroll
  for (int off = 32; off > 0; off >>= 1) {
    s  += __shfl_down(s,  off, 64);
    ss += __shfl_down(ss, off, 64);
  }
  __shared__ float ps[4], pss[4];
  int wave = t >> 6, lane = t & 63;
  if (lane == 0) { ps[wave] = s; pss[wave] = ss; }
  __syncthreads();
  float tot  = ps[0] + ps[1] + ps[2] + ps[3];
  float tot2 = pss[0] + pss[1] + pss[2] + pss[3];
  float mu   = tot * (1.0f / DMODEL);
  float var  = tot2 * (1.0f / DMODEL) - mu * mu;
  float rstd = rsqrtf(var + 1e-6f);
  float4 g  = *reinterpret_cast<const float4*>(gamma + t * 4);
  float4 bb = *reinterpret_cast<const float4*>(beta  + t * 4);
  bf16x4 o;
  o[0] = (__bf16)((v.x - mu) * rstd * g.x + bb.x);
  o[1] = (__bf16)((v.y - mu) * rstd * g.y + bb.y);
  o[2] = (__bf16)((v.z - mu) * rstd * g.z + bb.z);
  o[3] = (__bf16)((v.w - mu) * rstd * g.w + bb.w);
  *reinterpret_cast<bf16x4*>(qn + (size_t)row * DMODEL + t * 4) = o;
}

// ---------------------------------------------------------------- cast k,v -> bf16
__global__ __launch_bounds__(256) void castkv_kernel(const float* __restrict__ k,
    const float* __restrict__ v, __bf16* __restrict__ kb, __bf16* __restrict__ vb)
{
  const float* src = blockIdx.y ? v : k;
  __bf16* dst = blockIdx.y ? vb : kb;
  size_t i = ((size_t)blockIdx.x * 256 + threadIdx.x) * 8;
  float4 a = *reinterpret_cast<const float4*>(src + i);
  float4 b = *reinterpret_cast<const float4*>(src + i + 4);
  bf16x8 o;
  o[0] = (__bf16)a.x; o[1] = (__bf16)a.y; o[2] = (__bf16)a.z; o[3] = (__bf16)a.w;
  o[4] = (__bf16)b.x; o[5] = (__bf16)b.y; o[6] = (__bf16)b.z; o[7] = (__bf16)b.w;
  *reinterpret_cast<bf16x8*>(dst + i) = o;
}

// ------------------------------------------- cast + transpose weights -> bf16 W^T
__global__ __launch_bounds__(256) void wt_kernel(
    const float* __restrict__ W0, const float* __restrict__ W1,
    const float* __restrict__ W2, const float* __restrict__ W3,
    __bf16* __restrict__ T0, __bf16* __restrict__ T1,
    __bf16* __restrict__ T2, __bf16* __restrict__ T3)
{
  const float* Ws[4] = {W0, W1, W2, W3};
  __bf16* Ts[4] = {T0, T1, T2, T3};
  const float* W = Ws[blockIdx.z];
  __bf16* T = Ts[blockIdx.z];
  __shared__ float lds[64][65];
  int n0 = blockIdx.x * 64, k0 = blockIdx.y * 64;
  int tx = threadIdx.x & 63, ty = threadIdx.x >> 6;
#pragma unroll
  for (int r = 0; r < 16; r++)
    lds[ty + r * 4][tx] = W[(size_t)(k0 + ty + r * 4) * DMODEL + n0 + tx];
  __syncthreads();
#pragma unroll
  for (int r = 0; r < 16; r++)
    T[(size_t)(n0 + ty + r * 4) * DMODEL + k0 + tx] = (__bf16)lds[tx][ty + r * 4];
}

// ---------------------------------------------------------------- GEMM  C = A @ Bt^T
// MODE 2 only now: write fp32 dst[row*1024+col] = acc + residual[row*1024+col]
template <int MODE>
__global__ __launch_bounds__(256) void gemm_bt(const __bf16* __restrict__ A,
    const __bf16* __restrict__ Bt, void* __restrict__ dst,
    const float* __restrict__ residual)
{
  constexpr int K = DMODEL;
  __shared__ __bf16 As[128 * 40];
  __shared__ __bf16 Bs[128 * 40];
  int n0 = blockIdx.x * 128, m0 = blockIdx.y * 128;
  int t = threadIdx.x, wave = t >> 6, lane = t & 63;
  int lane15 = lane & 15, quad = lane >> 4;
  int wm = (wave & 1) * 64, wn = (wave >> 1) * 64;
  int arow = t >> 2, akk = (t & 3) * 8;
  f32x4 acc[4][4] = {};
  for (int k0 = 0; k0 < K; k0 += 32) {
#pragma unroll
    for (int p = 0; p < 2; p++) {
      int row = arow + p * 64;
      bf16x8 ta = *reinterpret_cast<const bf16x8*>(A  + (size_t)(m0 + row) * K + k0 + akk);
      bf16x8 tb = *reinterpret_cast<const bf16x8*>(Bt + (size_t)(n0 + row) * K + k0 + akk);
      *reinterpret_cast<bf16x8*>(&As[row * 40 + akk]) = ta;
      *reinterpret_cast<bf16x8*>(&Bs[row * 40 + akk]) = tb;
    }
    __syncthreads();
    bf16x8 af[4], bf[4];
#pragma unroll
    for (int i = 0; i < 4; i++)
      af[i] = *reinterpret_cast<bf16x8*>(&As[(wm + i * 16 + lane15) * 40 + quad * 8]);
#pragma unroll
    for (int j = 0; j < 4; j++)
      bf[j] = *reinterpret_cast<bf16x8*>(&Bs[(wn + j * 16 + lane15) * 40 + quad * 8]);
#pragma unroll
    for (int i = 0; i < 4; i++)
#pragma unroll
      for (int j = 0; j < 4; j++)
        acc[i][j] = __builtin_amdgcn_mfma_f32_16x16x32_bf16(af[i], bf[j], acc[i][j], 0, 0, 0);
    __syncthreads();
  }
#pragma unroll
  for (int i = 0; i < 4; i++) {
#pragma unroll
    for (int j = 0; j < 4; j++) {
      int col = n0 + wn + j * 16 + lane15;
#pragma unroll
      for (int r = 0; r < 4; r++) {
        int row = m0 + wm + i * 16 + quad * 4 + r;
        float val = acc[i][j][r];
        if (MODE == 2) {
          float* o = (float*)dst;
          o[(size_t)row * DMODEL + col] = val + residual[(size_t)row * DMODEL + col];
        } else {
          int b = row >> 11, s = row & 2047, h = col >> 6, d = col & 63;
          __bf16* o = (__bf16*)dst;
          if (MODE == 0)
            o[(((size_t)(b * NHEAD + h)) * SLEN + s) * DKV + d] = (__bf16)val;
          else
            o[(((size_t)(b * NHEAD + h)) * DKV + d) * SLEN + s] = (__bf16)val;
        }
      }
    }
  }
}

// -------------------------------------------------- fused QKV projection GEMM
// z=0: qn@Wqt -> qh (head layout), z=1: kb@Wkt -> kh (head layout),
// z=2: vb@Wvt -> vht (transposed head layout).  3x blocks resident vs 3 launches.
__global__ __launch_bounds__(256) void gemm_qkv(
    const __bf16* __restrict__ A0, const __bf16* __restrict__ A1, const __bf16* __restrict__ A2,
    const __bf16* __restrict__ B0, const __bf16* __restrict__ B1, const __bf16* __restrict__ B2,
    __bf16* __restrict__ D0, __bf16* __restrict__ D1, __bf16* __restrict__ D2)
{
  constexpr int K = DMODEL;
  __shared__ __bf16 As[128 * 40];
  __shared__ __bf16 Bs[128 * 40];
  int z = blockIdx.z;
  const __bf16* A  = (z == 0) ? A0 : (z == 1) ? A1 : A2;
  const __bf16* Bt = (z == 0) ? B0 : (z == 1) ? B1 : B2;
  __bf16* dst      = (z == 0) ? D0 : (z == 1) ? D1 : D2;
  bool transp = (z == 2);
  int n0 = blockIdx.x * 128, m0 = blockIdx.y * 128;
  int t = threadIdx.x, wave = t >> 6, lane = t & 63;
  int lane15 = lane & 15, quad = lane >> 4;
  int wm = (wave & 1) * 64, wn = (wave >> 1) * 64;
  int arow = t >> 2, akk = (t & 3) * 8;
  f32x4 acc[4][4] = {};
  for (int k0 = 0; k0 < K; k0 += 32) {
#pragma unroll
    for (int p = 0; p < 2; p++) {
      int row = arow + p * 64;
      bf16x8 ta = *reinterpret_cast<const bf16x8*>(A  + (size_t)(m0 + row) * K + k0 + akk);
      bf16x8 tb = *reinterpret_cast<const bf16x8*>(Bt + (size_t)(n0 + row) * K + k0 + akk);
      *reinterpret_cast<bf16x8*>(&As[row * 40 + akk]) = ta;
      *reinterpret_cast<bf16x8*>(&Bs[row * 40 + akk]) = tb;
    }
    __syncthreads();
    bf16x8 af[4], bf[4];
#pragma unroll
    for (int i = 0; i < 4; i++)
      af[i] = *reinterpret_cast<bf16x8*>(&As[(wm + i * 16 + lane15) * 40 + quad * 8]);
#pragma unroll
    for (int j = 0; j < 4; j++)
      bf[j] = *reinterpret_cast<bf16x8*>(&Bs[(wn + j * 16 + lane15) * 40 + quad * 8]);
#pragma unroll
    for (int i = 0; i < 4; i++)
#pragma unroll
      for (int j = 0; j < 4; j++)
        acc[i][j] = __builtin_amdgcn_mfma_f32_16x16x32_bf16(af[i], bf[j], acc[i][j], 0, 0, 0);
    __syncthreads();
  }
#pragma unroll
  for (int i = 0; i < 4; i++) {
#pragma unroll
    for (int j = 0; j < 4; j++) {
      int col = n0 + wn + j * 16 + lane15;
#pragma unroll
      for (int r = 0; r < 4; r++) {
        int row = m0 + wm + i * 16 + quad * 4 + r;
        float val = acc[i][j][r];
        int b = row >> 11, s = row & 2047, h = col >> 6, d = col & 63;
        if (!transp)
          dst[(((size_t)(b * NHEAD + h)) * SLEN + s) * DKV + d] = (__bf16)val;
        else
          dst[(((size_t)(b * NHEAD + h)) * DKV + d) * SLEN + s] = (__bf16)val;
      }
    }
  }
}

// ---------------------------------------------------------------- fused attention
// Swapped-operand MFMA: S^T = mfma(K,Q) so each lane owns one q-row (lane&15)
// and 4 CONSECUTIVE k-cols (quad*4+r) -> int4 mask loads, float4 attn stores,
// bf16x4 LDS parks.  PV swapped too (O^T = mfma(V^T, S)) -> bf16x4 epilogue.
// 512 threads (8 waves x 16 q-rows), 2 blocks/CU, ~47% occupancy.
__global__ __launch_bounds__(512, 4) void attn_kernel(const __bf16* __restrict__ qh,
    const __bf16* __restrict__ kh, const __bf16* __restrict__ vht,
    const int* __restrict__ mask, __bf16* __restrict__ attn_o,
    float* __restrict__ attn_out)
{
  __shared__ __bf16 lds[18432]; // 36864 B: [0,9216) Q then K+V, [9216,18432) S park
  int t = threadIdx.x, wave = t >> 6, lane = t & 63;
  int lane15 = lane & 15, quad = lane >> 4;
  int bh = blockIdx.y, b = bh >> 4, h = bh & 15;
  int q0 = blockIdx.x * 128;

  const __bf16* qp = qh  + (size_t)bh * SLEN * DKV;
  const __bf16* kp = kh  + (size_t)bh * SLEN * DKV;
  const __bf16* vp = vht + (size_t)bh * DKV * SLEN;

  // stage Q tile (128 x 64), stride 72
  int srow = t >> 3, skk = (t & 7) * 8;   // srow in 0..63
#pragma unroll
  for (int p = 0; p < 2; p++) {
    int row = srow + p * 64;
    *reinterpret_cast<bf16x8*>(&lds[row * 72 + skk]) =
        *reinterpret_cast<const bf16x8*>(qp + (size_t)(q0 + row) * DKV + skk);
  }
  __syncthreads();
  bf16x8 qf[2];
#pragma unroll
  for (int ks = 0; ks < 2; ks++)
    qf[ks] = *reinterpret_cast<bf16x8*>(
        &lds[(wave * 16 + lane15) * 72 + ks * 32 + quad * 8]);
  __syncthreads();

  int gq = q0 + wave * 16 + lane15;                    // this lane's q row
  const int* mrow = mask + (size_t)b * SLEN * SLEN + (size_t)gq * SLEN;
  float* arow = attn_out + ((size_t)bh * SLEN + gq) * SLEN;
  int srowQ = wave * 16 + lane15;                      // S-park row

  f32x4 oacc[4] = {};

  for (int k0 = 0; k0 < SLEN; k0 += 64) {
    // stage K chunk (64 x 64) at lds[0], V chunk (64dv x 64seq) at lds[4608]
    *reinterpret_cast<bf16x8*>(&lds[srow * 72 + skk]) =
        *reinterpret_cast<const bf16x8*>(kp + (size_t)(k0 + srow) * DKV + skk);
    *reinterpret_cast<bf16x8*>(&lds[4608 + srow * 72 + skk]) =
        *reinterpret_cast<const bf16x8*>(vp + (size_t)srow * SLEN + k0 + skk);
    __syncthreads();

    // ---- S^T = K Q^T : lane holds S[gq][k0 + j*16 + quad*4 + r]
    f32x4 sacc[4] = {};
#pragma unroll
    for (int ks = 0; ks < 2; ks++) {
      bf16x8 kf[4];
#pragma unroll
      for (int j = 0; j < 4; j++)
        kf[j] = *reinterpret_cast<bf16x8*>(
            &lds[(j * 16 + lane15) * 72 + ks * 32 + quad * 8]);
#pragma unroll
      for (int j = 0; j < 4; j++)
        sacc[j] = __builtin_amdgcn_mfma_f32_16x16x32_bf16(kf[j], qf[ks], sacc[j], 0, 0, 0);
    }

    // scale, mask (int4), emit fp32 attn (float4), park bf16 S (b64)
#pragma unroll
    for (int j = 0; j < 4; j++) {
      int kb_ = j * 16 + quad * 4;
      i32x4 m4 = *reinterpret_cast<const i32x4*>(mrow + k0 + kb_);
      f32x4 sv;
      bf16x4 pk;
#pragma unroll
      for (int r = 0; r < 4; r++) {
        float x = sacc[j][r] * INV_TEMP;
        x = (m4[r] == 0) ? -1e9f : x;
        sv[r] = x;
        pk[r] = (__bf16)x;
      }
      *reinterpret_cast<f32x4*>(arow + k0 + kb_) = sv;
      *reinterpret_cast<bf16x4*>(&lds[9216 + srowQ * 72 + kb_]) = pk;
    }
    __syncthreads();

    // ---- O^T += V^T S^T  (lane holds O[gq][d = j*16 + quad*4 + r])
#pragma unroll
    for (int kc = 0; kc < 2; kc++) {
      bf16x8 sa = *reinterpret_cast<bf16x8*>(
          &lds[9216 + srowQ * 72 + kc * 32 + quad * 8]);
      bf16x8 vb[4];
#pragma unroll
      for (int j = 0; j < 4; j++)
        vb[j] = *reinterpret_cast<bf16x8*>(
            &lds[4608 + (j * 16 + lane15) * 72 + kc * 32 + quad * 8]);
#pragma unroll
      for (int j = 0; j < 4; j++)
        oacc[j] = __builtin_amdgcn_mfma_f32_16x16x32_bf16(vb[j], sa, oacc[j], 0, 0, 0);
    }
    __syncthreads();
  }

  // epilogue: attn_o row-major (4096, 1024) bf16, bf16x4 stores
#pragma unroll
  for (int j = 0; j < 4; j++) {
    bf16x4 o4;
#pragma unroll
    for (int r = 0; r < 4; r++) o4[r] = (__bf16)oacc[j][r];
    *reinterpret_cast<bf16x4*>(
        &attn_o[(size_t)(b * SLEN + gq) * DMODEL + h * DKV + j * 16 + quad * 4]) = o4;
  }
}

// ---------------------------------------------------------------- launch
extern "C" void kernel_launch(void* const* d_in, const int* in_sizes, int n_in,
                              void* d_out, int out_size, void* d_ws, size_t ws_size,
                              hipStream_t stream) {
  const float* q    = (const float*)d_in[0];
  const float* k    = (const float*)d_in[1];
  const float* v    = (const float*)d_in[2];
  const int*   mask = (const int*)d_in[3];
  const float* Wq   = (const float*)d_in[4];
  const float* Wk   = (const float*)d_in[5];
  const float* Wv   = (const float*)d_in[6];
  const float* Wfc  = (const float*)d_in[7];
  const float* gamma = (const float*)d_in[8];
  const float* beta  = (const float*)d_in[9];
  float* out_f = (float*)d_out;

  char* w = (char*)d_ws;
  const size_t MB = 1024 * 1024;
  __bf16* qn   = (__bf16*)(w + 0);        // 8 MB (4096x1024)
  __bf16* kb   = (__bf16*)(w + 8  * MB);  // 8 MB
  __bf16* vb   = (__bf16*)(w + 16 * MB);  // 8 MB
  __bf16* Wqt  = (__bf16*)(w + 24 * MB);  // 2 MB each
  __bf16* Wkt  = (__bf16*)(w + 26 * MB);
  __bf16* Wvt  = (__bf16*)(w + 28 * MB);
  __bf16* Wfct = (__bf16*)(w + 30 * MB);
  __bf16* qh   = (__bf16*)(w + 32 * MB);  // 8 MB (B,H,S,64)
  __bf16* kh   = (__bf16*)(w + 40 * MB);  // 8 MB (B,H,S,64)
  __bf16* vht  = (__bf16*)(w + 48 * MB);  // 8 MB (B,H,64,S)
  __bf16* atto = (__bf16*)(w + 0);        // aliases qn (dead by then): 8 MB

  ln_kernel<<<NROWS, 256, 0, stream>>>(q, gamma, beta, qn);
  castkv_kernel<<<dim3(2048, 2), 256, 0, stream>>>(k, v, kb, vb);
  wt_kernel<<<dim3(16, 16, 4), 256, 0, stream>>>(Wq, Wk, Wv, Wfc, Wqt, Wkt, Wvt, Wfct);

  gemm_qkv<<<dim3(8, 32, 3), 256, 0, stream>>>(qn, kb, vb, Wqt, Wkt, Wvt, qh, kh, vht);

  attn_kernel<<<dim3(16, 32), 512, 0, stream>>>(qh, kh, vht, mask, atto,
                                                out_f + (size_t)NROWS * DMODEL);

  gemm_bt<2><<<dim3(8, 32), 256, 0, stream>>>(atto, Wfct, (void*)out_f, q);
}